// Round 3
// baseline (430.001 us; speedup 1.0000x reference)
//
#include <hip/hip_runtime.h>

typedef short short8 __attribute__((ext_vector_type(8)));
typedef float floatx4 __attribute__((ext_vector_type(4)));

__device__ __forceinline__ unsigned short f2bf(float f) {
  unsigned int u = __float_as_uint(f);
  u += 0x7FFFu + ((u >> 16) & 1u);   // RNE
  return (unsigned short)(u >> 16);
}

// ---------------------------------------------------------------------------
// Weight repack: f32 -> bf16 MFMA fragments (layout notes in R1).
// ---------------------------------------------------------------------------
__global__ void prep_weights(const float* __restrict__ W1x, const float* __restrict__ W1p,
                             const float* __restrict__ W2x, unsigned short* __restrict__ wbuf) {
  int i = blockIdx.x * 256 + threadIdx.x;
  if (i >= 49152) return;
  float v;
  if (i < 40960) {
    const float* W = (i < 20480) ? W1x : W1p;
    int j = (i < 20480) ? i : i - 20480;
    int jj   = j & 7;
    int lane = (j >> 3) & 63;
    int ks   = (j >> 9) % 5;
    int nt   = j / 2560;
    int k = ks*32 + (lane >> 4)*8 + jj;
    int n = nt*16 + (lane & 15);
    v = (k < 129) ? W[k*128 + n] : 0.0f;
  } else {
    int j = i - 40960;
    int jj   = j & 7;
    int lane = (j >> 3) & 63;
    int ks   = (j >> 9) & 3;
    int nt   = j >> 11;
    int k = ks*32 + (lane >> 4)*8 + jj;
    int n = nt*16 + (lane & 15);
    v = W2x[k*64 + n];
  }
  wbuf[i] = f2bf(v);
}

// ---------------------------------------------------------------------------
// Counting sort by destination (col): hist -> scan -> scatter (packed int2)
// ---------------------------------------------------------------------------
__global__ void k_hist(const int* __restrict__ col, int E, int* __restrict__ hist) {
  int i = blockIdx.x * 256 + threadIdx.x;
  if (i < E) atomicAdd(&hist[col[i]], 1);
}

__global__ __launch_bounds__(256) void k_scan_a(const int* __restrict__ hist, int N,
                                                int* __restrict__ excl, int* __restrict__ bsum) {
  __shared__ int wtot[4], wexc[4];
  int t = threadIdx.x, lane = t & 63, w = t >> 6;
  int base = blockIdx.x * 1024 + t * 4;
  int v0 = (base + 0 < N) ? hist[base + 0] : 0;
  int v1 = (base + 1 < N) ? hist[base + 1] : 0;
  int v2 = (base + 2 < N) ? hist[base + 2] : 0;
  int v3 = (base + 3 < N) ? hist[base + 3] : 0;
  int T = v0 + v1 + v2 + v3;
  int inc = T;
  #pragma unroll
  for (int s = 1; s < 64; s <<= 1) {
    int u = __shfl_up(inc, s, 64);
    if (lane >= s) inc += u;
  }
  if (lane == 63) wtot[w] = inc;
  __syncthreads();
  if (t == 0) {
    int a = 0;
    #pragma unroll
    for (int i = 0; i < 4; ++i) { wexc[i] = a; a += wtot[i]; }
    bsum[blockIdx.x] = a;
  }
  __syncthreads();
  int tex = wexc[w] + (inc - T);
  if (base + 0 < N) excl[base + 0] = tex;
  if (base + 1 < N) excl[base + 1] = tex + v0;
  if (base + 2 < N) excl[base + 2] = tex + v0 + v1;
  if (base + 3 < N) excl[base + 3] = tex + v0 + v1 + v2;
}

__global__ void k_scan_b(const int* __restrict__ bsum, int* __restrict__ boff, int NB) {
  int lane = threadIdx.x;                    // single wave of 64
  int v = (lane < NB) ? bsum[lane] : 0;
  int inc = v;
  #pragma unroll
  for (int s = 1; s < 64; s <<= 1) {
    int u = __shfl_up(inc, s, 64);
    if (lane >= s) inc += u;
  }
  if (lane < NB) boff[lane] = inc - v;
}

__global__ void k_scan_c(int* __restrict__ excl, const int* __restrict__ boff, int N,
                         int* __restrict__ cursor) {
  int i = blockIdx.x * 256 + threadIdx.x;
  if (i < N) { int v = excl[i] + boff[i >> 10]; excl[i] = v; cursor[i] = v; }
}

__global__ void k_scatter(const int* __restrict__ row, const int* __restrict__ col, int E,
                          int* __restrict__ cursor, int2* __restrict__ sedge) {
  int i = blockIdx.x * 256 + threadIdx.x;
  if (i < E) {
    int c = col[i];
    int p = atomicAdd(&cursor[c], 1);
    sedge[p] = make_int2(row[i], c);
  }
}

// ---------------------------------------------------------------------------
// Main fused kernel: persistent-ish blocks. Each block loops over TILES=8
// tiles of 64 (col-sorted) edges; weight fragments stay in registers across
// tiles (amortizes 96 KB/block of fragment reloads and grid dispatch).
// Transposed GEMMs, persistent weight A-fragments (see R1); segmented
// suffix-sum epilogue over sorted cols (see R2).
// ---------------------------------------------------------------------------
#define TILES 8

__global__ __launch_bounds__(256) void mp_main(
    const float* __restrict__ x, const float* __restrict__ pos,
    const int2* __restrict__ sedge,
    const int* __restrict__ rowp, const int* __restrict__ colp,
    int E, int sorted,
    const float* __restrict__ b1x, const float* __restrict__ b2x,
    const float* __restrict__ b1p, const float* __restrict__ W2p,
    const float* __restrict__ b2p,
    const unsigned short* __restrict__ wbuf,
    float* __restrict__ out_x, float* __restrict__ out_pos)
{
  __shared__ __align__(16) unsigned short C_lds[64][168];
  __shared__ __align__(16) unsigned short H_lds[64][136];
  __shared__ float rel_lds[64][3];
  __shared__ int   col_sh[64];
  __shared__ float wsum[4][64];

  const int t    = threadIdx.x;
  const int wv   = t >> 6;
  const int lane = t & 63;
  const int quad = lane >> 4;
  const int lc   = lane & 15;

  const short8* __restrict__ w1x_f = (const short8*)(wbuf);
  const short8* __restrict__ w1p_f = (const short8*)(wbuf + 20480);
  const short8* __restrict__ w2x_f = (const short8*)(wbuf + 40960);

  // persistent weight A-fragments (live across all tiles)
  short8 a1x[2][5], a1p[2][5], a2w[4];
  #pragma unroll
  for (int i = 0; i < 2; ++i) {
    int hti = wv + 4*i;
    #pragma unroll
    for (int ks = 0; ks < 5; ++ks) {
      a1x[i][ks] = w1x_f[(hti*5 + ks)*64 + lane];
      a1p[i][ks] = w1p_f[(hti*5 + ks)*64 + lane];
    }
  }
  #pragma unroll
  for (int ks = 0; ks < 4; ++ks) a2w[ks] = w2x_f[(wv*4 + ks)*64 + lane];

  float bx[2][4], bp[2][4], wp2[2][4], b2xr[4];
  #pragma unroll
  for (int i = 0; i < 2; ++i)
    #pragma unroll
    for (int r = 0; r < 4; ++r) {
      int h = (wv + 4*i)*16 + quad*4 + r;
      bx[i][r] = b1x[h]; bp[i][r] = b1p[h]; wp2[i][r] = W2p[h];
    }
  #pragma unroll
  for (int r = 0; r < 4; ++r) b2xr[r] = b2x[wv*16 + quad*4 + r];
  const float b2ps = b2p[0];

  #pragma unroll 1
  for (int ti = 0; ti < TILES; ++ti) {
    const int e0 = (blockIdx.x * TILES + ti) * 64;
    if (e0 >= E) break;                       // uniform across block
    __syncthreads();                          // prev tile's consumers done

    // ---- phase 1: per-edge scalars + combined-feature staging (bf16) ----
    if (t < 64) {
      int e = e0 + t;
      float rp0 = 0.f, rp1 = 0.f, rp2 = 0.f, dsq = 0.f; int c = -1;
      if (e < E) {
        int r;
        if (sorted) { int2 rc = sedge[e]; r = rc.x; c = rc.y; }
        else        { r = rowp[e]; c = colp[e]; }
        float pr0 = pos[r*3+0], pr1 = pos[r*3+1], pr2 = pos[r*3+2];
        float pc0 = pos[c*3+0], pc1 = pos[c*3+1], pc2 = pos[c*3+2];
        rp0 = pr0 - pc0; rp1 = pr1 - pc1; rp2 = pr2 - pc2;
        dsq = rp0*rp0 + rp1*rp1 + rp2*rp2;
      }
      rel_lds[t][0] = rp0; rel_lds[t][1] = rp1; rel_lds[t][2] = rp2;
      col_sh[t] = c;
      C_lds[t][128] = f2bf(dsq);
      #pragma unroll
      for (int k = 129; k < 160; ++k) C_lds[t][k] = 0;
    }
    {
      const int s = t >> 2, p = t & 3;     // 4 threads/edge, 16 floats each
      const int e = e0 + s;
      unsigned int vr[8], vc[8];
      if (e < E) {
        int r, c;
        if (sorted) { int2 rc = sedge[e]; r = rc.x; c = rc.y; }
        else        { r = rowp[e]; c = colp[e]; }
        const float4* xr = (const float4*)(x + (size_t)r*64 + p*16);
        const float4* xc = (const float4*)(x + (size_t)c*64 + p*16);
        #pragma unroll
        for (int q = 0; q < 4; ++q) {
          float4 a = xr[q];
          vr[q*2+0] = (unsigned)f2bf(a.x) | ((unsigned)f2bf(a.y) << 16);
          vr[q*2+1] = (unsigned)f2bf(a.z) | ((unsigned)f2bf(a.w) << 16);
          float4 b = xc[q];
          vc[q*2+0] = (unsigned)f2bf(b.x) | ((unsigned)f2bf(b.y) << 16);
          vc[q*2+1] = (unsigned)f2bf(b.z) | ((unsigned)f2bf(b.w) << 16);
        }
      } else {
        #pragma unroll
        for (int q = 0; q < 8; ++q) { vr[q] = 0u; vc[q] = 0u; }
      }
      uint4* d0 = (uint4*)&C_lds[s][p*16];
      d0[0] = make_uint4(vr[0], vr[1], vr[2], vr[3]);
      d0[1] = make_uint4(vr[4], vr[5], vr[6], vr[7]);
      uint4* d1 = (uint4*)&C_lds[s][64 + p*16];
      d1[0] = make_uint4(vc[0], vc[1], vc[2], vc[3]);
      d1[1] = make_uint4(vc[4], vc[5], vc[6], vc[7]);
    }
    __syncthreads();

    // ---- GEMM1 (x & p fused), silu, H^T -> LDS, phi_p dot ----
    #pragma unroll 1
    for (int et = 0; et < 4; ++et) {
      floatx4 ax0 = {0,0,0,0}, ax1 = {0,0,0,0}, ap0 = {0,0,0,0}, ap1 = {0,0,0,0};
      #pragma unroll
      for (int ks = 0; ks < 5; ++ks) {
        short8 b = *(const short8*)&C_lds[et*16 + lc][ks*32 + quad*8];
        ax0 = __builtin_amdgcn_mfma_f32_16x16x32_bf16(a1x[0][ks], b, ax0, 0, 0, 0);
        ax1 = __builtin_amdgcn_mfma_f32_16x16x32_bf16(a1x[1][ks], b, ax1, 0, 0, 0);
        ap0 = __builtin_amdgcn_mfma_f32_16x16x32_bf16(a1p[0][ks], b, ap0, 0, 0, 0);
        ap1 = __builtin_amdgcn_mfma_f32_16x16x32_bf16(a1p[1][ks], b, ap1, 0, 0, 0);
      }
      float ps = 0.f;
      #pragma unroll
      for (int i = 0; i < 2; ++i) {
        floatx4 axx = i ? ax1 : ax0;
        floatx4 app = i ? ap1 : ap0;
        unsigned int packed[2];
        #pragma unroll
        for (int r = 0; r < 4; r += 2) {
          float h0 = axx[r]   + bx[i][r];
          float h1 = axx[r+1] + bx[i][r+1];
          float s0 = h0 * __builtin_amdgcn_rcpf(1.f + __expf(-h0));
          float s1 = h1 * __builtin_amdgcn_rcpf(1.f + __expf(-h1));
          packed[r >> 1] = (unsigned)f2bf(s0) | ((unsigned)f2bf(s1) << 16);
        }
        *(uint2*)&H_lds[et*16 + lc][(wv + 4*i)*16 + quad*4] = make_uint2(packed[0], packed[1]);
        #pragma unroll
        for (int r = 0; r < 4; ++r) {
          float h  = app[r] + bp[i][r];
          float sv = h * __builtin_amdgcn_rcpf(1.f + __expf(-h));
          ps += sv * wp2[i][r];
        }
      }
      ps += __shfl_xor(ps, 16, 64);
      ps += __shfl_xor(ps, 32, 64);
      if (lane < 16) wsum[wv][et*16 + lane] = ps;
    }
    __syncthreads();

    // ---- GEMM2 + segmented-reduce scatter ----
    #pragma unroll 1
    for (int et = 0; et < 4; ++et) {
      floatx4 acc = {0,0,0,0};
      #pragma unroll
      for (int ks = 0; ks < 4; ++ks) {
        short8 b = *(const short8*)&H_lds[et*16 + lc][ks*32 + quad*8];
        acc = __builtin_amdgcn_mfma_f32_16x16x32_bf16(a2w[ks], b, acc, 0, 0, 0);
      }
      int edge = et*16 + lc;
      int myc = col_sh[edge];
      float v0 = acc[0] + b2xr[0], v1 = acc[1] + b2xr[1];
      float v2 = acc[2] + b2xr[2], v3 = acc[3] + b2xr[3];
      if (sorted) {
        #pragma unroll
        for (int s = 1; s < 16; s <<= 1) {
          int   nc  = __shfl_down(myc, s, 64);
          float n0  = __shfl_down(v0,  s, 64);
          float n1  = __shfl_down(v1,  s, 64);
          float n2  = __shfl_down(v2,  s, 64);
          float n3  = __shfl_down(v3,  s, 64);
          if ((lc + s < 16) && (nc == myc)) { v0 += n0; v1 += n1; v2 += n2; v3 += n3; }
        }
      }
      bool head = (myc >= 0) && (!sorted || lc == 0 || col_sh[edge-1] != myc);
      if (head) {
        float* dst = out_x + (size_t)myc*64 + wv*16 + quad*4;
        atomicAdd(dst + 0, v0);
        atomicAdd(dst + 1, v1);
        atomicAdd(dst + 2, v2);
        atomicAdd(dst + 3, v3);
      }
    }

    // ---- phi_p epilogue: weight * rel_pos, segmented over 64 sorted edges --
    if (t < 64) {
      int c = col_sh[t];
      float w = wsum[0][t] + wsum[1][t] + wsum[2][t] + wsum[3][t] + b2ps;
      float p0 = w * rel_lds[t][0], p1 = w * rel_lds[t][1], p2 = w * rel_lds[t][2];
      if (sorted) {
        #pragma unroll
        for (int s = 1; s < 64; s <<= 1) {
          int   nc = __shfl_down(c,  s, 64);
          float n0 = __shfl_down(p0, s, 64);
          float n1 = __shfl_down(p1, s, 64);
          float n2 = __shfl_down(p2, s, 64);
          if ((t + s < 64) && (nc == c)) { p0 += n0; p1 += n1; p2 += n2; }
        }
      }
      bool head = (c >= 0) && (!sorted || t == 0 || col_sh[t-1] != c);
      if (head) {
        atomicAdd(&out_pos[(size_t)c*3 + 0], p0);
        atomicAdd(&out_pos[(size_t)c*3 + 1], p1);
        atomicAdd(&out_pos[(size_t)c*3 + 2], p2);
      }
    }
  }
}

extern "C" void kernel_launch(void* const* d_in, const int* in_sizes, int n_in,
                              void* d_out, int out_size, void* d_ws, size_t ws_size,
                              hipStream_t stream) {
  const float* x   = (const float*)d_in[0];
  const float* pos = (const float*)d_in[1];
  const int*   ei  = (const int*)d_in[2];
  const float* W1x = (const float*)d_in[3];
  const float* b1x = (const float*)d_in[4];
  const float* W2x = (const float*)d_in[5];
  const float* b2x = (const float*)d_in[6];
  const float* W1p = (const float*)d_in[7];
  const float* b1p = (const float*)d_in[8];
  const float* W2p = (const float*)d_in[9];
  const float* b2p = (const float*)d_in[10];

  const int E = in_sizes[2] / 2;        // 800000
  const int N = in_sizes[0] / 64;       // 50000
  const int* rowp = ei;
  const int* colp = ei + E;
  float* out_x   = (float*)d_out;
  float* out_pos = out_x + (size_t)N * 64;

  char* ws = (char*)d_ws;
  const size_t o_wbuf   = 0;                       // 98304 B
  const size_t o_off    = 98304;                   // N*4 -> 200000, pad 200192
  const size_t o_cursor = o_off + 200192;          // 200192
  const size_t o_bsum   = o_cursor + 200192;       // 512
  const size_t o_boff   = o_bsum + 512;            // 512
  const size_t o_sedge  = o_boff + 512;            // E*8 = 6400000
  const size_t ws_need  = o_sedge + (size_t)E * 8;

  unsigned short* wbuf = (unsigned short*)(ws + o_wbuf);
  int*  off    = (int*)(ws + o_off);
  int*  cursor = (int*)(ws + o_cursor);
  int*  bsum   = (int*)(ws + o_bsum);
  int*  boff   = (int*)(ws + o_boff);
  int2* sedge  = (int2*)(ws + o_sedge);

  const int use_sort = (ws_size >= ws_need) ? 1 : 0;

  hipMemsetAsync(d_out, 0, (size_t)out_size * sizeof(float), stream);
  prep_weights<<<192, 256, 0, stream>>>(W1x, W1p, W2x, wbuf);

  if (use_sort) {
    const int NB = (N + 1023) / 1024;   // 49 (<=64 assumed)
    hipMemsetAsync(off, 0, (size_t)N * sizeof(int), stream);
    k_hist<<<(E + 255) / 256, 256, 0, stream>>>(colp, E, off);
    k_scan_a<<<NB, 256, 0, stream>>>(off, N, off, bsum);
    k_scan_b<<<1, 64, 0, stream>>>(bsum, boff, NB);
    k_scan_c<<<(N + 255) / 256, 256, 0, stream>>>(off, boff, N, cursor);
    k_scatter<<<(E + 255) / 256, 256, 0, stream>>>(rowp, colp, E, cursor, sedge);
  }

  const int nblk = (E + TILES*64 - 1) / (TILES*64);
  mp_main<<<nblk, 256, 0, stream>>>(x, pos, sedge, rowp, colp, E, use_sort,
                                    b1x, b2x, b1p, W2p, b2p,
                                    wbuf, out_x, out_pos);
}

// Round 4
// 348.892 us; speedup vs baseline: 1.2325x; 1.2325x over previous
//
#include <hip/hip_runtime.h>

typedef short short8 __attribute__((ext_vector_type(8)));
typedef float floatx4 __attribute__((ext_vector_type(4)));

__device__ __forceinline__ unsigned short f2bf(float f) {
  unsigned int u = __float_as_uint(f);
  u += 0x7FFFu + ((u >> 16) & 1u);   // RNE
  return (unsigned short)(u >> 16);
}

#if __has_builtin(__builtin_amdgcn_cvt_pk_bf16_f32)
typedef __bf16 bf16x2_t __attribute__((ext_vector_type(2)));
__device__ __forceinline__ unsigned int pk2bf(float lo, float hi) {
  bf16x2_t v = __builtin_amdgcn_cvt_pk_bf16_f32(lo, hi);
  return __builtin_bit_cast(unsigned int, v);
}
#else
__device__ __forceinline__ unsigned int pk2bf(float lo, float hi) {
  return (unsigned)f2bf(lo) | ((unsigned)f2bf(hi) << 16);
}
#endif

// ---------------------------------------------------------------------------
// x (f32) -> bf16, once. Removes per-edge cvt work from mp_main phase 1.
// ---------------------------------------------------------------------------
__global__ void k_xcvt(const float* __restrict__ x, unsigned short* __restrict__ xb, int n) {
  int i = (blockIdx.x * 256 + threadIdx.x) * 8;
  if (i < n) {
    float4 a = *(const float4*)(x + i);
    float4 b = *(const float4*)(x + i + 4);
    uint4 o;
    o.x = pk2bf(a.x, a.y); o.y = pk2bf(a.z, a.w);
    o.z = pk2bf(b.x, b.y); o.w = pk2bf(b.z, b.w);
    *(uint4*)(xb + i) = o;
  }
}

// ---------------------------------------------------------------------------
// Weight repack: f32 -> bf16 MFMA fragments (layout notes in R1).
// NEW: bias folded in as K-row 129 (C[:,129]=1.0 in mp_main).
// ---------------------------------------------------------------------------
__global__ void prep_weights(const float* __restrict__ W1x, const float* __restrict__ W1p,
                             const float* __restrict__ b1x, const float* __restrict__ b1p,
                             const float* __restrict__ W2x, unsigned short* __restrict__ wbuf) {
  int i = blockIdx.x * 256 + threadIdx.x;
  if (i >= 49152) return;
  float v;
  if (i < 40960) {
    const float* W = (i < 20480) ? W1x : W1p;
    const float* B = (i < 20480) ? b1x : b1p;
    int j = (i < 20480) ? i : i - 20480;
    int jj   = j & 7;
    int lane = (j >> 3) & 63;
    int ks   = (j >> 9) % 5;
    int nt   = j / 2560;
    int k = ks*32 + (lane >> 4)*8 + jj;
    int n = nt*16 + (lane & 15);
    v = (k < 129) ? W[k*128 + n] : (k == 129 ? B[n] : 0.0f);
  } else {
    int j = i - 40960;
    int jj   = j & 7;
    int lane = (j >> 3) & 63;
    int ks   = (j >> 9) & 3;
    int nt   = j >> 11;
    int k = ks*32 + (lane >> 4)*8 + jj;
    int n = nt*16 + (lane & 15);
    v = W2x[k*64 + n];
  }
  wbuf[i] = f2bf(v);
}

// ---------------------------------------------------------------------------
// Counting sort by destination (col): hist -> scan -> scatter (packed int2)
// ---------------------------------------------------------------------------
__global__ void k_hist(const int* __restrict__ col, int E, int* __restrict__ hist) {
  int i = blockIdx.x * 256 + threadIdx.x;
  if (i < E) atomicAdd(&hist[col[i]], 1);
}

__global__ __launch_bounds__(256) void k_scan_a(const int* __restrict__ hist, int N,
                                                int* __restrict__ excl, int* __restrict__ bsum) {
  __shared__ int wtot[4], wexc[4];
  int t = threadIdx.x, lane = t & 63, w = t >> 6;
  int base = blockIdx.x * 1024 + t * 4;
  int v0 = (base + 0 < N) ? hist[base + 0] : 0;
  int v1 = (base + 1 < N) ? hist[base + 1] : 0;
  int v2 = (base + 2 < N) ? hist[base + 2] : 0;
  int v3 = (base + 3 < N) ? hist[base + 3] : 0;
  int T = v0 + v1 + v2 + v3;
  int inc = T;
  #pragma unroll
  for (int s = 1; s < 64; s <<= 1) {
    int u = __shfl_up(inc, s, 64);
    if (lane >= s) inc += u;
  }
  if (lane == 63) wtot[w] = inc;
  __syncthreads();
  if (t == 0) {
    int a = 0;
    #pragma unroll
    for (int i = 0; i < 4; ++i) { wexc[i] = a; a += wtot[i]; }
    bsum[blockIdx.x] = a;
  }
  __syncthreads();
  int tex = wexc[w] + (inc - T);
  if (base + 0 < N) excl[base + 0] = tex;
  if (base + 1 < N) excl[base + 1] = tex + v0;
  if (base + 2 < N) excl[base + 2] = tex + v0 + v1;
  if (base + 3 < N) excl[base + 3] = tex + v0 + v1 + v2;
}

__global__ void k_scan_b(const int* __restrict__ bsum, int* __restrict__ boff, int NB) {
  int lane = threadIdx.x;                    // single wave of 64
  int v = (lane < NB) ? bsum[lane] : 0;
  int inc = v;
  #pragma unroll
  for (int s = 1; s < 64; s <<= 1) {
    int u = __shfl_up(inc, s, 64);
    if (lane >= s) inc += u;
  }
  if (lane < NB) boff[lane] = inc - v;
}

__global__ void k_scatter(const int* __restrict__ row, const int* __restrict__ col, int E,
                          int* __restrict__ excl, const int* __restrict__ boff,
                          int2* __restrict__ sedge) {
  int i = blockIdx.x * 256 + threadIdx.x;
  if (i < E) {
    int c = col[i];
    int p = atomicAdd(&excl[c], 1) + boff[c >> 10];
    sedge[p] = make_int2(row[i], c);
  }
}

// ---------------------------------------------------------------------------
// Main fused kernel (R2 structure: 64 sorted edges/block, 256 threads).
// Transposed GEMMs, persistent weight A-fragments; biases via K-row 129;
// segmented suffix-sum epilogue over sorted cols.
// ---------------------------------------------------------------------------
__global__ __launch_bounds__(256) void mp_main(
    const float* __restrict__ x, const unsigned short* __restrict__ xb, int use_xb,
    const float* __restrict__ pos,
    const int2* __restrict__ sedge,
    const int* __restrict__ rowp, const int* __restrict__ colp,
    int E, int sorted,
    const float* __restrict__ b2x, const float* __restrict__ W2p,
    const float* __restrict__ b2p,
    const unsigned short* __restrict__ wbuf,
    float* __restrict__ out_x, float* __restrict__ out_pos)
{
  __shared__ __align__(16) unsigned short C_lds[64][168];
  __shared__ __align__(16) unsigned short H_lds[64][136];
  __shared__ float rel_lds[64][3];
  __shared__ int   col_sh[64];
  __shared__ float wsum[4][64];

  const int t    = threadIdx.x;
  const int e0   = blockIdx.x * 64;
  const int wv   = t >> 6;
  const int lane = t & 63;
  const int quad = lane >> 4;
  const int lc   = lane & 15;

  // ---- phase 1: per-edge scalars + combined-feature staging (bf16) ----
  if (t < 64) {
    int e = e0 + t;
    float rp0 = 0.f, rp1 = 0.f, rp2 = 0.f, dsq = 0.f; int c = -1;
    if (e < E) {
      int r;
      if (sorted) { int2 rc = sedge[e]; r = rc.x; c = rc.y; }
      else        { r = rowp[e]; c = colp[e]; }
      float pr0 = pos[r*3+0], pr1 = pos[r*3+1], pr2 = pos[r*3+2];
      float pc0 = pos[c*3+0], pc1 = pos[c*3+1], pc2 = pos[c*3+2];
      rp0 = pr0 - pc0; rp1 = pr1 - pc1; rp2 = pr2 - pc2;
      dsq = rp0*rp0 + rp1*rp1 + rp2*rp2;
    }
    rel_lds[t][0] = rp0; rel_lds[t][1] = rp1; rel_lds[t][2] = rp2;
    col_sh[t] = c;
    C_lds[t][128] = f2bf(dsq);
    C_lds[t][129] = 0x3F80;            // 1.0 -> multiplies folded bias row
    #pragma unroll
    for (int k = 130; k < 160; ++k) C_lds[t][k] = 0;
  }
  {
    const int s = t >> 2, p = t & 3;     // 4 threads/edge, 16 feats each side
    const int e = e0 + s;
    uint4 r0, r1, c0, c1;
    if (e < E) {
      int r, c;
      if (sorted) { int2 rc = sedge[e]; r = rc.x; c = rc.y; }
      else        { r = rowp[e]; c = colp[e]; }
      if (use_xb) {
        const uint4* xr = (const uint4*)(xb + (size_t)r*64 + p*16);
        const uint4* xc = (const uint4*)(xb + (size_t)c*64 + p*16);
        r0 = xr[0]; r1 = xr[1];
        c0 = xc[0]; c1 = xc[1];
      } else {
        const float4* xr = (const float4*)(x + (size_t)r*64 + p*16);
        const float4* xc = (const float4*)(x + (size_t)c*64 + p*16);
        float4 a0 = xr[0], a1 = xr[1], a2 = xr[2], a3 = xr[3];
        float4 d0 = xc[0], d1 = xc[1], d2 = xc[2], d3 = xc[3];
        r0 = make_uint4(pk2bf(a0.x,a0.y), pk2bf(a0.z,a0.w), pk2bf(a1.x,a1.y), pk2bf(a1.z,a1.w));
        r1 = make_uint4(pk2bf(a2.x,a2.y), pk2bf(a2.z,a2.w), pk2bf(a3.x,a3.y), pk2bf(a3.z,a3.w));
        c0 = make_uint4(pk2bf(d0.x,d0.y), pk2bf(d0.z,d0.w), pk2bf(d1.x,d1.y), pk2bf(d1.z,d1.w));
        c1 = make_uint4(pk2bf(d2.x,d2.y), pk2bf(d2.z,d2.w), pk2bf(d3.x,d3.y), pk2bf(d3.z,d3.w));
      }
    } else {
      r0 = r1 = c0 = c1 = make_uint4(0u, 0u, 0u, 0u);
    }
    uint4* dr = (uint4*)&C_lds[s][p*16];
    dr[0] = r0; dr[1] = r1;
    uint4* dc = (uint4*)&C_lds[s][64 + p*16];
    dc[0] = c0; dc[1] = c1;
  }
  __syncthreads();

  // ---- phase 2 ----
  const short8* __restrict__ w1x_f = (const short8*)(wbuf);
  const short8* __restrict__ w1p_f = (const short8*)(wbuf + 20480);
  const short8* __restrict__ w2x_f = (const short8*)(wbuf + 40960);

  short8 a1x[2][5], a1p[2][5], a2w[4];
  #pragma unroll
  for (int i = 0; i < 2; ++i) {
    int hti = wv + 4*i;
    #pragma unroll
    for (int ks = 0; ks < 5; ++ks) {
      a1x[i][ks] = w1x_f[(hti*5 + ks)*64 + lane];
      a1p[i][ks] = w1p_f[(hti*5 + ks)*64 + lane];
    }
  }
  #pragma unroll
  for (int ks = 0; ks < 4; ++ks) a2w[ks] = w2x_f[(wv*4 + ks)*64 + lane];

  float wp2[2][4], b2xr[4];
  #pragma unroll
  for (int i = 0; i < 2; ++i)
    #pragma unroll
    for (int r = 0; r < 4; ++r) wp2[i][r] = W2p[(wv + 4*i)*16 + quad*4 + r];
  #pragma unroll
  for (int r = 0; r < 4; ++r) b2xr[r] = b2x[wv*16 + quad*4 + r];
  const float b2ps = b2p[0];

  // GEMM1 (x & p fused over shared B-fragment), silu, H^T -> LDS, phi_p dot
  #pragma unroll 2
  for (int et = 0; et < 4; ++et) {
    floatx4 ax0 = {0,0,0,0}, ax1 = {0,0,0,0}, ap0 = {0,0,0,0}, ap1 = {0,0,0,0};
    #pragma unroll
    for (int ks = 0; ks < 5; ++ks) {
      short8 b = *(const short8*)&C_lds[et*16 + lc][ks*32 + quad*8];
      ax0 = __builtin_amdgcn_mfma_f32_16x16x32_bf16(a1x[0][ks], b, ax0, 0, 0, 0);
      ax1 = __builtin_amdgcn_mfma_f32_16x16x32_bf16(a1x[1][ks], b, ax1, 0, 0, 0);
      ap0 = __builtin_amdgcn_mfma_f32_16x16x32_bf16(a1p[0][ks], b, ap0, 0, 0, 0);
      ap1 = __builtin_amdgcn_mfma_f32_16x16x32_bf16(a1p[1][ks], b, ap1, 0, 0, 0);
    }
    float ps = 0.f;
    #pragma unroll
    for (int i = 0; i < 2; ++i) {
      floatx4 axx = i ? ax1 : ax0;
      floatx4 app = i ? ap1 : ap0;
      float sx[4];
      #pragma unroll
      for (int r = 0; r < 4; ++r) {
        float h  = axx[r];                                 // bias already in
        sx[r] = h * __builtin_amdgcn_rcpf(1.f + __expf(-h));
        float hp = app[r];
        float sp = hp * __builtin_amdgcn_rcpf(1.f + __expf(-hp));
        ps += sp * wp2[i][r];
      }
      *(uint2*)&H_lds[et*16 + lc][(wv + 4*i)*16 + quad*4] =
          make_uint2(pk2bf(sx[0], sx[1]), pk2bf(sx[2], sx[3]));
    }
    ps += __shfl_xor(ps, 16, 64);
    ps += __shfl_xor(ps, 32, 64);
    if (lane < 16) wsum[wv][et*16 + lane] = ps;
  }
  __syncthreads();

  // GEMM2: MSG^T = W2x^T @ H^T, segmented-reduce over sorted cols, scatter
  #pragma unroll 2
  for (int et = 0; et < 4; ++et) {
    floatx4 acc = {0,0,0,0};
    #pragma unroll
    for (int ks = 0; ks < 4; ++ks) {
      short8 b = *(const short8*)&H_lds[et*16 + lc][ks*32 + quad*8];
      acc = __builtin_amdgcn_mfma_f32_16x16x32_bf16(a2w[ks], b, acc, 0, 0, 0);
    }
    int edge = et*16 + lc;
    int myc = col_sh[edge];
    float v0 = acc[0] + b2xr[0], v1 = acc[1] + b2xr[1];
    float v2 = acc[2] + b2xr[2], v3 = acc[3] + b2xr[3];
    if (sorted) {
      #pragma unroll
      for (int s = 1; s < 16; s <<= 1) {
        int   nc  = __shfl_down(myc, s, 64);
        float n0  = __shfl_down(v0,  s, 64);
        float n1  = __shfl_down(v1,  s, 64);
        float n2  = __shfl_down(v2,  s, 64);
        float n3  = __shfl_down(v3,  s, 64);
        if ((lc + s < 16) && (nc == myc)) { v0 += n0; v1 += n1; v2 += n2; v3 += n3; }
      }
    }
    bool head = (myc >= 0) && (!sorted || lc == 0 || col_sh[edge-1] != myc);
    if (head) {
      float* dst = out_x + (size_t)myc*64 + wv*16 + quad*4;
      atomicAdd(dst + 0, v0);
      atomicAdd(dst + 1, v1);
      atomicAdd(dst + 2, v2);
      atomicAdd(dst + 3, v3);
    }
  }

  // phi_p epilogue: weight * rel_pos, segmented over 64 sorted edges
  if (t < 64) {
    int c = col_sh[t];
    float w = wsum[0][t] + wsum[1][t] + wsum[2][t] + wsum[3][t] + b2ps;
    float p0 = w * rel_lds[t][0], p1 = w * rel_lds[t][1], p2 = w * rel_lds[t][2];
    if (sorted) {
      #pragma unroll
      for (int s = 1; s < 64; s <<= 1) {
        int   nc = __shfl_down(c,  s, 64);
        float n0 = __shfl_down(p0, s, 64);
        float n1 = __shfl_down(p1, s, 64);
        float n2 = __shfl_down(p2, s, 64);
        if ((t + s < 64) && (nc == c)) { p0 += n0; p1 += n1; p2 += n2; }
      }
    }
    bool head = (c >= 0) && (!sorted || t == 0 || col_sh[t-1] != c);
    if (head) {
      atomicAdd(&out_pos[(size_t)c*3 + 0], p0);
      atomicAdd(&out_pos[(size_t)c*3 + 1], p1);
      atomicAdd(&out_pos[(size_t)c*3 + 2], p2);
    }
  }
}

extern "C" void kernel_launch(void* const* d_in, const int* in_sizes, int n_in,
                              void* d_out, int out_size, void* d_ws, size_t ws_size,
                              hipStream_t stream) {
  const float* x   = (const float*)d_in[0];
  const float* pos = (const float*)d_in[1];
  const int*   ei  = (const int*)d_in[2];
  const float* W1x = (const float*)d_in[3];
  const float* b1x = (const float*)d_in[4];
  const float* W2x = (const float*)d_in[5];
  const float* b2x = (const float*)d_in[6];
  const float* W1p = (const float*)d_in[7];
  const float* b1p = (const float*)d_in[8];
  const float* W2p = (const float*)d_in[9];
  const float* b2p = (const float*)d_in[10];

  const int E = in_sizes[2] / 2;        // 800000
  const int N = in_sizes[0] / 64;       // 50000
  const int* rowp = ei;
  const int* colp = ei + E;
  float* out_x   = (float*)d_out;
  float* out_pos = out_x + (size_t)N * 64;

  char* ws = (char*)d_ws;
  const size_t xb_bytes = (size_t)N * 64 * 2;        // 6,400,000
  // Try layout A (with bf16-x cache); fall back to layout B without it.
  size_t base = 0;
  int use_xb = 0;
  {
    // need: xb + wbuf + off + bsum + boff + sedge
    size_t needA = xb_bytes + 98304 + 200192 + 512 + 512 + (size_t)E * 8;
    if (ws_size >= needA) { use_xb = 1; base = xb_bytes; }
  }
  unsigned short* xb   = (unsigned short*)ws;
  unsigned short* wbuf = (unsigned short*)(ws + base);
  int*  off   = (int*)(ws + base + 98304);
  int*  bsum  = (int*)(ws + base + 98304 + 200192);
  int*  boff  = (int*)(ws + base + 98304 + 200192 + 512);
  int2* sedge = (int2*)(ws + base + 98304 + 200192 + 1024);
  const size_t need_sort = base + 98304 + 200192 + 1024 + (size_t)E * 8;
  const int use_sort = (ws_size >= need_sort) ? 1 : 0;

  hipMemsetAsync(d_out, 0, (size_t)out_size * sizeof(float), stream);
  if (use_xb)
    k_xcvt<<<(N*64 + 2047) / 2048, 256, 0, stream>>>(x, xb, N*64);
  prep_weights<<<192, 256, 0, stream>>>(W1x, W1p, b1x, b1p, W2x, wbuf);

  if (use_sort) {
    const int NB = (N + 1023) / 1024;   // 49 (<=64 assumed)
    hipMemsetAsync(off, 0, (size_t)N * sizeof(int), stream);
    k_hist<<<(E + 255) / 256, 256, 0, stream>>>(colp, E, off);
    k_scan_a<<<NB, 256, 0, stream>>>(off, N, off, bsum);
    k_scan_b<<<1, 64, 0, stream>>>(bsum, boff, NB);
    k_scatter<<<(E + 255) / 256, 256, 0, stream>>>(rowp, colp, E, off, boff, sedge);
  }

  mp_main<<<(E + 63) / 64, 256, 0, stream>>>(x, xb, use_xb, pos, sedge, rowp, colp,
                                             E, use_sort, b2x, W2p, b2p,
                                             wbuf, out_x, out_pos);
}